// Round 5
// baseline (372.678 us; speedup 1.0000x reference)
//
#include <hip/hip_runtime.h>
#include <hip/hip_bf16.h>

typedef __bf16 bf16;
typedef __bf16 bf16x4 __attribute__((ext_vector_type(4)));
typedef __bf16 bf16x8 __attribute__((ext_vector_type(8)));
typedef float f32x4 __attribute__((ext_vector_type(4)));

#define GLP(p) ((const __attribute__((address_space(1))) void*)(p))
#define LDSP(p) ((__attribute__((address_space(3))) void*)(p))

// ---------------- fp32 -> bf16 convert ----------------
__global__ __launch_bounds__(256) void cvt_kernel(const float* __restrict__ in,
                                                  bf16* __restrict__ out, int n4) {
  int i = blockIdx.x * 256 + threadIdx.x;
  if (i < n4) {
    float4 v = reinterpret_cast<const float4*>(in)[i];
    bf16x4 o = { (bf16)v.x, (bf16)v.y, (bf16)v.z, (bf16)v.w };
    reinterpret_cast<bf16x4*>(out)[i] = o;
  }
}

// ---------------- fused QKV GEMM ----------------
// C[4096,3072] = Xb[4096,1024] @ Wb[3072,1024]^T + bias
// Epilogue scatters: Q,K -> [BH][S][64] bf16 ; V -> [BH][64][S] bf16 (transposed)
__global__ __launch_bounds__(256) void qkv_gemm(
    const bf16* __restrict__ Xb, const bf16* __restrict__ Wb,
    const float* __restrict__ biasq, const float* __restrict__ biask,
    const float* __restrict__ biasv,
    bf16* __restrict__ Qb, bf16* __restrict__ Kb, bf16* __restrict__ Vt) {
  __shared__ __align__(16) bf16 As[128 * 32];
  __shared__ __align__(16) bf16 Bs[128 * 32];
  const int tid = threadIdx.x;
  const int w = tid >> 6, l = tid & 63;
  const int lg = l >> 4, lr = l & 15;
  const int wr = w >> 1, wc = w & 1;
  const int bm = blockIdx.y * 128, bn = blockIdx.x * 128;

  f32x4 acc[4][4] = {};

  #pragma unroll 1
  for (int k0 = 0; k0 < 1024; k0 += 32) {
    #pragma unroll
    for (int i = 0; i < 2; ++i) {
      int row = i * 64 + (tid >> 2);
      int c8 = (tid & 3) * 8;
      __builtin_amdgcn_global_load_lds(GLP(Xb + (bm + row) * 1024 + k0 + c8),
                                       LDSP((char*)As + (i * 256 + w * 64) * 16),
                                       16, 0, 0);
      __builtin_amdgcn_global_load_lds(GLP(Wb + (bn + row) * 1024 + k0 + c8),
                                       LDSP((char*)Bs + (i * 256 + w * 64) * 16),
                                       16, 0, 0);
    }
    __syncthreads();
    bf16x8 af[4], bfq[4];
    #pragma unroll
    for (int t = 0; t < 4; ++t) {
      af[t]  = *reinterpret_cast<const bf16x8*>(
                   reinterpret_cast<const char*>(As) + (wr * 64 + t * 16 + lr) * 64 + lg * 16);
      bfq[t] = *reinterpret_cast<const bf16x8*>(
                   reinterpret_cast<const char*>(Bs) + (wc * 64 + t * 16 + lr) * 64 + lg * 16);
    }
    #pragma unroll
    for (int mt = 0; mt < 4; ++mt)
      #pragma unroll
      for (int nt = 0; nt < 4; ++nt)
        acc[mt][nt] = __builtin_amdgcn_mfma_f32_16x16x32_bf16(af[mt], bfq[nt], acc[mt][nt], 0, 0, 0);
    __syncthreads();
  }

  // epilogue: block's n-range lies entirely in one of {Q,K,V} (1024 % 128 == 0)
  const int mtx = blockIdx.x >> 3;
  const float* bp = (mtx == 0) ? biasq : (mtx == 1) ? biask : biasv;
  #pragma unroll
  for (int nt = 0; nt < 4; ++nt) {
    int ng = bn + wc * 64 + nt * 16 + lr;
    int nj = ng & 1023;
    int hh = nj >> 6, d = nj & 63;
    float bias = bp[nj];
    #pragma unroll
    for (int mt = 0; mt < 4; ++mt) {
      int m0 = bm + wr * 64 + mt * 16 + lg * 4;
      int bb = m0 >> 11, s0 = m0 & 2047;
      if (mtx == 2) {
        bf16x4 pk;
        #pragma unroll
        for (int r = 0; r < 4; ++r) pk[r] = (bf16)(acc[mt][nt][r] + bias);
        *reinterpret_cast<bf16x4*>(Vt + (((bb * 16 + hh) * 64 + d) * 2048 + s0)) = pk;
      } else {
        bf16* dst = (mtx == 0) ? Qb : Kb;
        #pragma unroll
        for (int r = 0; r < 4; ++r)
          dst[((bb * 16 + hh) * 2048 + s0 + r) * 64 + d] = (bf16)(acc[mt][nt][r] + bias);
      }
    }
  }
}

// ---------------- flash attention (swapped QK^T: q on lanes, k in regs) ----
// Q,K: [BH][2048][64] bf16 ; Vt: [BH][64][2048] bf16 ; out fp32 [B][S][NH][64]
__global__ __launch_bounds__(256) void attn_kernel(
    const bf16* __restrict__ Qb, const bf16* __restrict__ Kb,
    const bf16* __restrict__ Vt, const float* __restrict__ mask,
    float* __restrict__ out) {
  __shared__ __align__(16) bf16 Pl[4][16 * 72];  // per-wave P tile, row stride 72 halves
  const int tid = threadIdx.x;
  const int w = tid >> 6, l = tid & 63;
  const int lg = l >> 4, lr = l & 15;
  // XCD swizzle: all 32 q-tiles of one (b,h) land on the same XCD -> K/V L2-resident
  const int blk = blockIdx.x;
  const int xcd = blk & 7, i0 = blk >> 3;
  const int bh = xcd * 4 + (i0 >> 5), qt = i0 & 31;
  const int bb = bh >> 4, hh = bh & 15;
  const int q16 = qt * 64 + w * 16;

  const bf16* Qp = Qb + (bh * 2048 + q16) * 64;
  const bf16* Kp = Kb + bh * 2048 * 64;
  const bf16* Vp = Vt + bh * 64 * 2048;
  const float* mp = mask + bb * 2048;

  // Q fragment (B-operand of swapped QK^T): col q = q16+lr, d = kk*32+lg*8..+7
  bf16x8 aq[2];
  #pragma unroll
  for (int kk = 0; kk < 2; ++kk)
    aq[kk] = *reinterpret_cast<const bf16x8*>(Qp + lr * 64 + kk * 32 + lg * 8);

  f32x4 acc[4] = {};          // PV out: d = nt*16+lr, q = q16 + lg*4 + r
  float mrun = -3.0e38f;      // softmax state for q = q16 + lr (replicated over lg)
  float lrun = 0.f;

  const float SC = 0.125f * 1.44269504f;   // 1/sqrt(64) * log2(e)
  const float MB = -10000.0f * 1.44269504f;
  bf16* pw = &Pl[w][0];

  #pragma unroll 1
  for (int kv0 = 0; kv0 < 2048; kv0 += 64) {
    // swapped QK^T: z = mfma(K_frag, Q_frag) -> col = q = lr, row = k = lg*4+r
    f32x4 sa[4];
    #pragma unroll
    for (int t = 0; t < 4; ++t) {
      f32x4 z = {};
      #pragma unroll
      for (int kk = 0; kk < 2; ++kk) {
        bf16x8 bk8 = *reinterpret_cast<const bf16x8*>(
            Kp + (kv0 + t * 16 + lr) * 64 + kk * 32 + lg * 8);
        z = __builtin_amdgcn_mfma_f32_16x16x32_bf16(bk8, aq[kk], z, 0, 0, 0);
      }
      sa[t] = z;
    }
    // scale + additive mask bias: k = kv0 + t*16 + lg*4 + r (vector mask load)
    #pragma unroll
    for (int t = 0; t < 4; ++t) {
      float4 mk = *reinterpret_cast<const float4*>(mp + kv0 + t * 16 + lg * 4);
      sa[t][0] = sa[t][0] * SC + (1.0f - mk.x) * MB;
      sa[t][1] = sa[t][1] * SC + (1.0f - mk.y) * MB;
      sa[t][2] = sa[t][2] * SC + (1.0f - mk.z) * MB;
      sa[t][3] = sa[t][3] * SC + (1.0f - mk.w) * MB;
    }
    // row max over 64 k's: 15 in-reg fmax + 2 cross-lane (lanes sharing lr)
    float rm = sa[0][0];
    #pragma unroll
    for (int t = 0; t < 4; ++t)
      #pragma unroll
      for (int r = 0; r < 4; ++r) rm = fmaxf(rm, sa[t][r]);
    rm = fmaxf(rm, __shfl_xor(rm, 16));
    rm = fmaxf(rm, __shfl_xor(rm, 32));
    float mn = fmaxf(mrun, rm);
    float fac = exp2f(mrun - mn);
    mrun = mn;
    // p = 2^(s-m), row sum
    float rs = 0.f;
    #pragma unroll
    for (int t = 0; t < 4; ++t)
      #pragma unroll
      for (int r = 0; r < 4; ++r) {
        float p = exp2f(sa[t][r] - mn);
        sa[t][r] = p;
        rs += p;
      }
    rs += __shfl_xor(rs, 16);
    rs += __shfl_xor(rs, 32);
    lrun = lrun * fac + rs;
    // broadcast fac from q=lr domain to acc's q=lg*4+r domain (4 bpermute)
    float facq[4];
    #pragma unroll
    for (int r = 0; r < 4; ++r) facq[r] = __shfl(fac, ((l >> 4) << 2) + r);
    #pragma unroll
    for (int nt = 0; nt < 4; ++nt)
      #pragma unroll
      for (int r = 0; r < 4; ++r) acc[nt][r] *= facq[r];
    // P -> LDS: row q=lr, col k=t*16+lg*4+r — packed 8B stores, A-frag layout
    #pragma unroll
    for (int t = 0; t < 4; ++t) {
      bf16x4 pk = { (bf16)sa[t][0], (bf16)sa[t][1], (bf16)sa[t][2], (bf16)sa[t][3] };
      *reinterpret_cast<bf16x4*>(pw + lr * 72 + t * 16 + lg * 4) = pk;
    }
    asm volatile("" ::: "memory");  // keep ds_write before ds_read (same-wave DS in-order)
    // PV: ctx[q][d] += P[q][k] * V[k][d]; V read transposed (contiguous k)
    #pragma unroll
    for (int ks = 0; ks < 2; ++ks) {
      bf16x8 pa = *reinterpret_cast<const bf16x8*>(
          reinterpret_cast<const char*>(pw) + lr * 144 + ks * 64 + lg * 16);
      #pragma unroll
      for (int nt = 0; nt < 4; ++nt) {
        bf16x8 bv8 = *reinterpret_cast<const bf16x8*>(
            Vp + (nt * 16 + lr) * 2048 + kv0 + ks * 32 + lg * 8);
        acc[nt] = __builtin_amdgcn_mfma_f32_16x16x32_bf16(pa, bv8, acc[nt], 0, 0, 0);
      }
    }
    asm volatile("" ::: "memory");
  }

  // epilogue: fetch l for q = lg*4+r, normalize, store
  #pragma unroll
  for (int r = 0; r < 4; ++r) {
    float lq = __shfl(lrun, ((l >> 4) << 2) + r);
    float inv = 1.0f / lq;
    int sq = q16 + lg * 4 + r;
    #pragma unroll
    for (int nt = 0; nt < 4; ++nt) {
      int d = nt * 16 + lr;
      out[((bb * 2048 + sq) * 16 + hh) * 64 + d] = acc[nt][r] * inv;
    }
  }
}

extern "C" void kernel_launch(void* const* d_in, const int* in_sizes, int n_in,
                              void* d_out, int out_size, void* d_ws, size_t ws_size,
                              hipStream_t stream) {
  const float* hs   = (const float*)d_in[0];
  const float* mask = (const float*)d_in[1];
  const float* Wq   = (const float*)d_in[2];
  const float* bq   = (const float*)d_in[3];
  const float* Wk   = (const float*)d_in[4];
  const float* bk   = (const float*)d_in[5];
  const float* Wv   = (const float*)d_in[6];
  const float* bv   = (const float*)d_in[7];
  float* out = (float*)d_out;

  // workspace layout (bf16 elems): Xb 4.19M | Wb 3.15M | Qb 4.19M | Kb 4.19M | Vt 4.19M
  if (ws_size < 39845888u) return;  // need ~40 MB
  bf16* Xb = (bf16*)d_ws;
  bf16* Wb = Xb + 4194304;
  bf16* Qb = Wb + 3145728;
  bf16* Kb = Qb + 4194304;
  bf16* Vt = Kb + 4194304;

  cvt_kernel<<<4096, 256, 0, stream>>>(hs, Xb, 1048576);
  cvt_kernel<<<1024, 256, 0, stream>>>(Wq, Wb, 262144);
  cvt_kernel<<<1024, 256, 0, stream>>>(Wk, Wb + 1048576, 262144);
  cvt_kernel<<<1024, 256, 0, stream>>>(Wv, Wb + 2097152, 262144);
  qkv_gemm<<<dim3(24, 32), 256, 0, stream>>>(Xb, Wb, bq, bk, bv, Qb, Kb, Vt);
  attn_kernel<<<1024, 256, 0, stream>>>(Qb, Kb, Vt, mask, out);
}

// Round 8
// 219.849 us; speedup vs baseline: 1.6952x; 1.6952x over previous
//
#include <hip/hip_runtime.h>
#include <hip/hip_bf16.h>

typedef __bf16 bf16;
typedef __bf16 bf16x4 __attribute__((ext_vector_type(4)));
typedef __bf16 bf16x8 __attribute__((ext_vector_type(8)));
typedef float f32x4 __attribute__((ext_vector_type(4)));

#define GLP(p) ((const __attribute__((address_space(1))) void*)(p))
#define LDSP(p) ((__attribute__((address_space(3))) void*)(p))

// ---------------- fp32 -> bf16 convert ----------------
__global__ __launch_bounds__(256) void cvt_kernel(const float* __restrict__ in,
                                                  bf16* __restrict__ out, int n4) {
  int i = blockIdx.x * 256 + threadIdx.x;
  if (i < n4) {
    float4 v = reinterpret_cast<const float4*>(in)[i];
    bf16x4 o = { (bf16)v.x, (bf16)v.y, (bf16)v.z, (bf16)v.w };
    reinterpret_cast<bf16x4*>(out)[i] = o;
  }
}

// ---------------- fused QKV GEMM ----------------
// C[4096,3072] = Xb[4096,1024] @ Wb[3072,1024]^T + bias
// Epilogue scatters: Q,K -> [BH][S][64] bf16 ; V -> [BH][64][S] bf16 (transposed)
__global__ __launch_bounds__(256) void qkv_gemm(
    const bf16* __restrict__ Xb, const bf16* __restrict__ Wb,
    const float* __restrict__ biasq, const float* __restrict__ biask,
    const float* __restrict__ biasv,
    bf16* __restrict__ Qb, bf16* __restrict__ Kb, bf16* __restrict__ Vt) {
  __shared__ __align__(16) bf16 As[128 * 32];
  __shared__ __align__(16) bf16 Bs[128 * 32];
  const int tid = threadIdx.x;
  const int w = tid >> 6, l = tid & 63;
  const int lg = l >> 4, lr = l & 15;
  const int wr = w >> 1, wc = w & 1;
  const int bm = blockIdx.y * 128, bn = blockIdx.x * 128;

  f32x4 acc[4][4] = {};

  #pragma unroll 1
  for (int k0 = 0; k0 < 1024; k0 += 32) {
    #pragma unroll
    for (int i = 0; i < 2; ++i) {
      int row = i * 64 + (tid >> 2);
      int c8 = (tid & 3) * 8;
      __builtin_amdgcn_global_load_lds(GLP(Xb + (bm + row) * 1024 + k0 + c8),
                                       LDSP((char*)As + (i * 256 + w * 64) * 16),
                                       16, 0, 0);
      __builtin_amdgcn_global_load_lds(GLP(Wb + (bn + row) * 1024 + k0 + c8),
                                       LDSP((char*)Bs + (i * 256 + w * 64) * 16),
                                       16, 0, 0);
    }
    __syncthreads();
    bf16x8 af[4], bfq[4];
    #pragma unroll
    for (int t = 0; t < 4; ++t) {
      af[t]  = *reinterpret_cast<const bf16x8*>(
                   reinterpret_cast<const char*>(As) + (wr * 64 + t * 16 + lr) * 64 + lg * 16);
      bfq[t] = *reinterpret_cast<const bf16x8*>(
                   reinterpret_cast<const char*>(Bs) + (wc * 64 + t * 16 + lr) * 64 + lg * 16);
    }
    #pragma unroll
    for (int mt = 0; mt < 4; ++mt)
      #pragma unroll
      for (int nt = 0; nt < 4; ++nt)
        acc[mt][nt] = __builtin_amdgcn_mfma_f32_16x16x32_bf16(af[mt], bfq[nt], acc[mt][nt], 0, 0, 0);
    __syncthreads();
  }

  // epilogue: block's n-range lies entirely in one of {Q,K,V} (1024 % 128 == 0)
  const int mtx = blockIdx.x >> 3;
  const float* bp = (mtx == 0) ? biasq : (mtx == 1) ? biask : biasv;
  #pragma unroll
  for (int nt = 0; nt < 4; ++nt) {
    int ng = bn + wc * 64 + nt * 16 + lr;
    int nj = ng & 1023;
    int hh = nj >> 6, d = nj & 63;
    float bias = bp[nj];
    #pragma unroll
    for (int mt = 0; mt < 4; ++mt) {
      int m0 = bm + wr * 64 + mt * 16 + lg * 4;
      int bb = m0 >> 11, s0 = m0 & 2047;
      if (mtx == 2) {
        bf16x4 pk;
        #pragma unroll
        for (int r = 0; r < 4; ++r) pk[r] = (bf16)(acc[mt][nt][r] + bias);
        *reinterpret_cast<bf16x4*>(Vt + (((bb * 16 + hh) * 64 + d) * 2048 + s0)) = pk;
      } else {
        bf16* dst = (mtx == 0) ? Qb : Kb;
        #pragma unroll
        for (int r = 0; r < 4; ++r)
          dst[((bb * 16 + hh) * 2048 + s0 + r) * 64 + d] = (bf16)(acc[mt][nt][r] + bias);
      }
    }
  }
}

// ---------------- flash attention (LDS-staged K/V, swapped QK^T) ----------
// Q,K: [BH][2048][64] bf16 ; Vt: [BH][64][2048] bf16 ; out fp32 [B][S][NH][64]
// K/V tiles staged once per block via global_load_lds with XOR-swizzle:
//   LDS row stride 128B; 16B chunk c of row r stored at chunk c^(r&7)
//   (linear LDS dest + pre-swizzled GLOBAL source; reads apply same XOR)
__global__ __launch_bounds__(256) void attn_kernel(
    const bf16* __restrict__ Qb, const bf16* __restrict__ Kb,
    const bf16* __restrict__ Vt, const float* __restrict__ mask,
    float* __restrict__ out) {
  __shared__ __align__(16) bf16 Ks[64 * 64];     // 8 KB K tile  [k][d]
  __shared__ __align__(16) bf16 Vs[64 * 64];     // 8 KB V tile  [d][s]
  __shared__ __align__(16) bf16 Pl[4][16 * 72];  // per-wave P tile
  const int tid = threadIdx.x;
  const int w = tid >> 6, l = tid & 63;
  const int lg = l >> 4, lr = l & 15;
  // XCD swizzle: all 32 q-tiles of one (b,h) land on the same XCD
  const int blk = blockIdx.x;
  const int xcd = blk & 7, i0 = blk >> 3;
  const int bh = xcd * 4 + (i0 >> 5), qt = i0 & 31;
  const int bb = bh >> 4, hh = bh & 15;
  const int q16 = qt * 64 + w * 16;

  const bf16* Qp = Qb + (bh * 2048 + q16) * 64;
  const bf16* Kp = Kb + bh * 2048 * 64;
  const bf16* Vp = Vt + bh * 64 * 2048;
  const float* mp = mask + bb * 2048;

  // Q fragment (B-operand of swapped QK^T): col q = q16+lr, d = kk*32+lg*8..+7
  bf16x8 aq[2];
  #pragma unroll
  for (int kk = 0; kk < 2; ++kk)
    aq[kk] = *reinterpret_cast<const bf16x8*>(Qp + lr * 64 + kk * 32 + lg * 8);

  f32x4 acc[4] = {};          // PV out: d = nt*16+lr, q = q16 + lg*4 + r
  float mrun = -3.0e38f;      // softmax state for q = q16 + lr (replicated over lg)
  float lrun = 0.f;

  const float SC = 0.125f * 1.44269504f;   // 1/sqrt(64) * log2(e)
  const float MB = -10000.0f * 1.44269504f;
  bf16* pw = &Pl[w][0];
  // staging indices (per thread): chunk idx = p*256+tid -> row=idx>>3, chunk=idx&7
  const int srow = tid >> 3, sch = tid & 7;

  #pragma unroll 1
  for (int kv0 = 0; kv0 < 2048; kv0 += 64) {
    // ---- stage K,V tile (16 KB) cooperatively; pre-swizzled global source ----
    #pragma unroll
    for (int p = 0; p < 2; ++p) {
      int rw = p * 32 + srow;
      int chg = sch ^ (rw & 7);
      __builtin_amdgcn_global_load_lds(GLP(Kp + (kv0 + rw) * 64 + chg * 8),
                                       LDSP((char*)Ks + (p * 256 + w * 64) * 16), 16, 0, 0);
      __builtin_amdgcn_global_load_lds(GLP(Vp + rw * 2048 + kv0 + chg * 8),
                                       LDSP((char*)Vs + (p * 256 + w * 64) * 16), 16, 0, 0);
    }
    __syncthreads();  // drains vmcnt -> tiles ready

    // swapped QK^T from LDS: z = mfma(K_frag, Q_frag) -> col q = lr, row k = lg*4+r
    f32x4 sa[4];
    #pragma unroll
    for (int t = 0; t < 4; ++t) {
      f32x4 z = {};
      #pragma unroll
      for (int kk = 0; kk < 2; ++kk) {
        bf16x8 bk8 = *reinterpret_cast<const bf16x8*>(
            reinterpret_cast<const char*>(Ks) + (t * 16 + lr) * 128 + ((kk * 4 + lg) ^ (lr & 7)) * 16);
        z = __builtin_amdgcn_mfma_f32_16x16x32_bf16(bk8, aq[kk], z, 0, 0, 0);
      }
      sa[t] = z;
    }
    // scale + additive mask bias: k = kv0 + t*16 + lg*4 + r
    #pragma unroll
    for (int t = 0; t < 4; ++t) {
      float4 mk = *reinterpret_cast<const float4*>(mp + kv0 + t * 16 + lg * 4);
      sa[t][0] = sa[t][0] * SC + (1.0f - mk.x) * MB;
      sa[t][1] = sa[t][1] * SC + (1.0f - mk.y) * MB;
      sa[t][2] = sa[t][2] * SC + (1.0f - mk.z) * MB;
      sa[t][3] = sa[t][3] * SC + (1.0f - mk.w) * MB;
    }
    // row max over 64 k's: 15 in-reg fmax + 2 cross-lane
    float rm = sa[0][0];
    #pragma unroll
    for (int t = 0; t < 4; ++t)
      #pragma unroll
      for (int r = 0; r < 4; ++r) rm = fmaxf(rm, sa[t][r]);
    rm = fmaxf(rm, __shfl_xor(rm, 16));
    rm = fmaxf(rm, __shfl_xor(rm, 32));
    float mn = fmaxf(mrun, rm);
    float fac = exp2f(mrun - mn);
    mrun = mn;
    // p = 2^(s-m), row sum
    float rs = 0.f;
    #pragma unroll
    for (int t = 0; t < 4; ++t)
      #pragma unroll
      for (int r = 0; r < 4; ++r) {
        float p = exp2f(sa[t][r] - mn);
        sa[t][r] = p;
        rs += p;
      }
    rs += __shfl_xor(rs, 16);
    rs += __shfl_xor(rs, 32);
    lrun = lrun * fac + rs;
    // broadcast fac from q=lr domain to acc's q=lg*4+r domain
    float facq[4];
    #pragma unroll
    for (int r = 0; r < 4; ++r) facq[r] = __shfl(fac, ((l >> 4) << 2) + r);
    #pragma unroll
    for (int nt = 0; nt < 4; ++nt)
      #pragma unroll
      for (int r = 0; r < 4; ++r) acc[nt][r] *= facq[r];
    // P -> LDS: row q=lr, col k=t*16+lg*4+r — packed 8B stores, A-frag layout
    #pragma unroll
    for (int t = 0; t < 4; ++t) {
      bf16x4 pk = { (bf16)sa[t][0], (bf16)sa[t][1], (bf16)sa[t][2], (bf16)sa[t][3] };
      *reinterpret_cast<bf16x4*>(pw + lr * 72 + t * 16 + lg * 4) = pk;
    }
    asm volatile("" ::: "memory");  // keep ds_write before ds_read (same-wave DS in-order)
    // PV: ctx[q][d] += P[q][k] * V[k][d]; V frag from LDS (swizzled)
    #pragma unroll
    for (int ks = 0; ks < 2; ++ks) {
      bf16x8 pa = *reinterpret_cast<const bf16x8*>(
          reinterpret_cast<const char*>(pw) + lr * 144 + ks * 64 + lg * 16);
      #pragma unroll
      for (int nt = 0; nt < 4; ++nt) {
        bf16x8 bv8 = *reinterpret_cast<const bf16x8*>(
            reinterpret_cast<const char*>(Vs) + (nt * 16 + lr) * 128 + ((ks * 4 + lg) ^ (lr & 7)) * 16);
        acc[nt] = __builtin_amdgcn_mfma_f32_16x16x32_bf16(pa, bv8, acc[nt], 0, 0, 0);
      }
    }
    __syncthreads();  // all waves done with Ks/Vs before next stage overwrites
  }

  // epilogue: fetch l for q = lg*4+r, normalize, store
  #pragma unroll
  for (int r = 0; r < 4; ++r) {
    float lq = __shfl(lrun, ((l >> 4) << 2) + r);
    float inv = 1.0f / lq;
    int sq = q16 + lg * 4 + r;
    #pragma unroll
    for (int nt = 0; nt < 4; ++nt) {
      int d = nt * 16 + lr;
      out[((bb * 2048 + sq) * 16 + hh) * 64 + d] = acc[nt][r] * inv;
    }
  }
}

extern "C" void kernel_launch(void* const* d_in, const int* in_sizes, int n_in,
                              void* d_out, int out_size, void* d_ws, size_t ws_size,
                              hipStream_t stream) {
  const float* hs   = (const float*)d_in[0];
  const float* mask = (const float*)d_in[1];
  const float* Wq   = (const float*)d_in[2];
  const float* bq   = (const float*)d_in[3];
  const float* Wk   = (const float*)d_in[4];
  const float* bk   = (const float*)d_in[5];
  const float* Wv   = (const float*)d_in[6];
  const float* bv   = (const float*)d_in[7];
  float* out = (float*)d_out;

  // workspace layout (bf16 elems): Xb 4.19M | Wb 3.15M | Qb 4.19M | Kb 4.19M | Vt 4.19M
  if (ws_size < 39845888u) return;  // need ~40 MB
  bf16* Xb = (bf16*)d_ws;
  bf16* Wb = Xb + 4194304;
  bf16* Qb = Wb + 3145728;
  bf16* Kb = Qb + 4194304;
  bf16* Vt = Kb + 4194304;

  cvt_kernel<<<4096, 256, 0, stream>>>(hs, Xb, 1048576);
  cvt_kernel<<<1024, 256, 0, stream>>>(Wq, Wb, 262144);
  cvt_kernel<<<1024, 256, 0, stream>>>(Wk, Wb + 1048576, 262144);
  cvt_kernel<<<1024, 256, 0, stream>>>(Wv, Wb + 2097152, 262144);
  qkv_gemm<<<dim3(24, 32), 256, 0, stream>>>(Xb, Wb, bq, bk, bv, Qb, Kb, Vt);
  attn_kernel<<<1024, 256, 0, stream>>>(Qb, Kb, Vt, mask, out);
}

// Round 13
// 201.361 us; speedup vs baseline: 1.8508x; 1.0918x over previous
//
#include <hip/hip_runtime.h>
#include <hip/hip_bf16.h>

typedef __bf16 bf16;
typedef __bf16 bf16x4 __attribute__((ext_vector_type(4)));
typedef __bf16 bf16x8 __attribute__((ext_vector_type(8)));
typedef float f32x4 __attribute__((ext_vector_type(4)));

#define GLP(p) ((const __attribute__((address_space(1))) void*)(p))
#define LDSP(p) ((__attribute__((address_space(3))) void*)(p))

// ---------------- fused fp32 -> bf16 convert (hs + Wq + Wk + Wv) ----------
// ranges (in float4 units): [0,1048576) hs->Xb ; then 3x262144 W->Wb slabs
__global__ __launch_bounds__(256) void cvt_all_kernel(
    const float* __restrict__ hs, const float* __restrict__ Wq,
    const float* __restrict__ Wk, const float* __restrict__ Wv,
    bf16* __restrict__ Xb, bf16* __restrict__ Wb) {
  int i = blockIdx.x * 256 + threadIdx.x;  // < 1835008
  const float* src;
  bf16* dst;
  int off;
  if (i < 1048576) {
    src = hs; dst = Xb; off = i;
  } else {
    int j = i - 1048576;
    int which = j >> 18;          // 0..2
    off = j & 262143;
    src = (which == 0) ? Wq : (which == 1) ? Wk : Wv;
    dst = Wb + (which << 20);     // 1048576 bf16 elems per W slab
  }
  float4 v = *reinterpret_cast<const float4*>(src + off * 4);
  bf16x4 o = { (bf16)v.x, (bf16)v.y, (bf16)v.z, (bf16)v.w };
  *reinterpret_cast<bf16x4*>(dst + off * 4) = o;
}

// ---------------- fused QKV GEMM ----------------
// C[4096,3072] = Xb[4096,1024] @ Wb[3072,1024]^T + bias
// Epilogue scatters: Q,K -> [BH][S][64] bf16 ; V -> [BH][64][S] bf16 (transposed)
// Q is pre-scaled by 1/sqrt(HD)*log2(e) so attention needs no per-score scaling.
__global__ __launch_bounds__(256) void qkv_gemm(
    const bf16* __restrict__ Xb, const bf16* __restrict__ Wb,
    const float* __restrict__ biasq, const float* __restrict__ biask,
    const float* __restrict__ biasv,
    bf16* __restrict__ Qb, bf16* __restrict__ Kb, bf16* __restrict__ Vt) {
  __shared__ __align__(16) bf16 As[128 * 32];
  __shared__ __align__(16) bf16 Bs[128 * 32];
  const int tid = threadIdx.x;
  const int w = tid >> 6, l = tid & 63;
  const int lg = l >> 4, lr = l & 15;
  const int wr = w >> 1, wc = w & 1;
  const int bm = blockIdx.y * 128, bn = blockIdx.x * 128;

  f32x4 acc[4][4] = {};

  #pragma unroll 1
  for (int k0 = 0; k0 < 1024; k0 += 32) {
    #pragma unroll
    for (int i = 0; i < 2; ++i) {
      int row = i * 64 + (tid >> 2);
      int c8 = (tid & 3) * 8;
      __builtin_amdgcn_global_load_lds(GLP(Xb + (bm + row) * 1024 + k0 + c8),
                                       LDSP((char*)As + (i * 256 + w * 64) * 16),
                                       16, 0, 0);
      __builtin_amdgcn_global_load_lds(GLP(Wb + (bn + row) * 1024 + k0 + c8),
                                       LDSP((char*)Bs + (i * 256 + w * 64) * 16),
                                       16, 0, 0);
    }
    __syncthreads();
    bf16x8 af[4], bfq[4];
    #pragma unroll
    for (int t = 0; t < 4; ++t) {
      af[t]  = *reinterpret_cast<const bf16x8*>(
                   reinterpret_cast<const char*>(As) + (wr * 64 + t * 16 + lr) * 64 + lg * 16);
      bfq[t] = *reinterpret_cast<const bf16x8*>(
                   reinterpret_cast<const char*>(Bs) + (wc * 64 + t * 16 + lr) * 64 + lg * 16);
    }
    #pragma unroll
    for (int mt = 0; mt < 4; ++mt)
      #pragma unroll
      for (int nt = 0; nt < 4; ++nt)
        acc[mt][nt] = __builtin_amdgcn_mfma_f32_16x16x32_bf16(af[mt], bfq[nt], acc[mt][nt], 0, 0, 0);
    __syncthreads();
  }

  // epilogue: block's n-range lies entirely in one of {Q,K,V} (1024 % 128 == 0)
  const int mtx = blockIdx.x >> 3;
  const float* bp = (mtx == 0) ? biasq : (mtx == 1) ? biask : biasv;
  const float scale = (mtx == 0) ? 0.18033688f : 1.0f;  // Q: 0.125 * log2(e)
  #pragma unroll
  for (int nt = 0; nt < 4; ++nt) {
    int ng = bn + wc * 64 + nt * 16 + lr;
    int nj = ng & 1023;
    int hh = nj >> 6, d = nj & 63;
    float bias = bp[nj];
    #pragma unroll
    for (int mt = 0; mt < 4; ++mt) {
      int m0 = bm + wr * 64 + mt * 16 + lg * 4;
      int bb = m0 >> 11, s0 = m0 & 2047;
      if (mtx == 2) {
        bf16x4 pk;
        #pragma unroll
        for (int r = 0; r < 4; ++r) pk[r] = (bf16)(acc[mt][nt][r] + bias);
        *reinterpret_cast<bf16x4*>(Vt + (((bb * 16 + hh) * 64 + d) * 2048 + s0)) = pk;
      } else {
        bf16* dst = (mtx == 0) ? Qb : Kb;
        #pragma unroll
        for (int r = 0; r < 4; ++r)
          dst[((bb * 16 + hh) * 2048 + s0 + r) * 64 + d] = (bf16)((acc[mt][nt][r] + bias) * scale);
      }
    }
  }
}

// ---------------- flash attention (LDS-staged K/V, swapped QK^T) ----------
// Q,K: [BH][2048][64] bf16 ; Vt: [BH][64][2048] bf16 ; out fp32 [B][S][NH][64]
// Q pre-scaled by 1/8*log2e -> scores are already in log2 domain.
// Mask hoisted: prologue scan; all-ones mask skips bias math entirely (exact).
// Defer-max: rescale only when tile max exceeds running max + 8.
__global__ __launch_bounds__(256) void attn_kernel(
    const bf16* __restrict__ Qb, const bf16* __restrict__ Kb,
    const bf16* __restrict__ Vt, const float* __restrict__ mask,
    float* __restrict__ out) {
  __shared__ __align__(16) bf16 Ks[64 * 64];     // 8 KB K tile  [k][d]
  __shared__ __align__(16) bf16 Vs[64 * 64];     // 8 KB V tile  [d][s]
  __shared__ __align__(16) bf16 Pl[4][16 * 72];  // per-wave P tile
  const int tid = threadIdx.x;
  const int w = tid >> 6, l = tid & 63;
  const int lg = l >> 4, lr = l & 15;
  // XCD swizzle: all 32 q-tiles of one (b,h) land on the same XCD
  const int blk = blockIdx.x;
  const int xcd = blk & 7, i0 = blk >> 3;
  const int bh = xcd * 4 + (i0 >> 5), qt = i0 & 31;
  const int bb = bh >> 4, hh = bh & 15;
  const int q16 = qt * 64 + w * 16;

  const bf16* Qp = Qb + (bh * 2048 + q16) * 64;
  const bf16* Kp = Kb + bh * 2048 * 64;
  const bf16* Vp = Vt + bh * 64 * 2048;
  const float* mp = mask + bb * 2048;

  // prologue: does this batch's mask have any zero? (wave-wide scan of 2048)
  bool nm = false;
  #pragma unroll
  for (int i = 0; i < 8; ++i) {
    float4 mv = *reinterpret_cast<const float4*>(mp + i * 256 + l * 4);
    nm |= (mv.x != 1.f) | (mv.y != 1.f) | (mv.z != 1.f) | (mv.w != 1.f);
  }
  const bool need_mask = __any(nm);

  // Q fragment (B-operand of swapped QK^T): col q = q16+lr, d = kk*32+lg*8..+7
  bf16x8 aq[2];
  #pragma unroll
  for (int kk = 0; kk < 2; ++kk)
    aq[kk] = *reinterpret_cast<const bf16x8*>(Qp + lr * 64 + kk * 32 + lg * 8);

  f32x4 acc[4] = {};          // PV out: d = nt*16+lr, q = q16 + lg*4 + r
  float mrun = -3.0e38f;      // softmax state for q = q16 + lr (replicated over lg)
  float lrun = 0.f;

  const float MB = -10000.0f * 1.44269504f;
  bf16* pw = &Pl[w][0];
  // staging indices (per thread): chunk idx = p*256+tid -> row=idx>>3, chunk=idx&7
  const int srow = tid >> 3, sch = tid & 7;

  #pragma unroll 1
  for (int kv0 = 0; kv0 < 2048; kv0 += 64) {
    // ---- stage K,V tile (16 KB) cooperatively; pre-swizzled global source ----
    #pragma unroll
    for (int p = 0; p < 2; ++p) {
      int rw = p * 32 + srow;
      int chg = sch ^ (rw & 7);
      __builtin_amdgcn_global_load_lds(GLP(Kp + (kv0 + rw) * 64 + chg * 8),
                                       LDSP((char*)Ks + (p * 256 + w * 64) * 16), 16, 0, 0);
      __builtin_amdgcn_global_load_lds(GLP(Vp + rw * 2048 + kv0 + chg * 8),
                                       LDSP((char*)Vs + (p * 256 + w * 64) * 16), 16, 0, 0);
    }
    __syncthreads();  // drains vmcnt -> tiles ready

    // swapped QK^T from LDS: z = mfma(K_frag, Q_frag) -> col q = lr, row k = lg*4+r
    f32x4 sa[4];
    #pragma unroll
    for (int t = 0; t < 4; ++t) {
      f32x4 z = {};
      #pragma unroll
      for (int kk = 0; kk < 2; ++kk) {
        bf16x8 bk8 = *reinterpret_cast<const bf16x8*>(
            reinterpret_cast<const char*>(Ks) + (t * 16 + lr) * 128 + ((kk * 4 + lg) ^ (lr & 7)) * 16);
        z = __builtin_amdgcn_mfma_f32_16x16x32_bf16(bk8, aq[kk], z, 0, 0, 0);
      }
      sa[t] = z;
    }
    // additive mask bias only when mask has zeros: k = kv0 + t*16 + lg*4 + r
    if (need_mask) {
      #pragma unroll
      for (int t = 0; t < 4; ++t) {
        float4 mk = *reinterpret_cast<const float4*>(mp + kv0 + t * 16 + lg * 4);
        sa[t][0] += (1.0f - mk.x) * MB;
        sa[t][1] += (1.0f - mk.y) * MB;
        sa[t][2] += (1.0f - mk.z) * MB;
        sa[t][3] += (1.0f - mk.w) * MB;
      }
    }
    // row max over 64 k's: pairwise tree (max3-friendly) + 2 cross-lane
    f32x4 mx01 = { fmaxf(sa[0][0], sa[1][0]), fmaxf(sa[0][1], sa[1][1]),
                   fmaxf(sa[0][2], sa[1][2]), fmaxf(sa[0][3], sa[1][3]) };
    f32x4 mx23 = { fmaxf(sa[2][0], sa[3][0]), fmaxf(sa[2][1], sa[3][1]),
                   fmaxf(sa[2][2], sa[3][2]), fmaxf(sa[2][3], sa[3][3]) };
    float rm = fmaxf(fmaxf(fmaxf(mx01[0], mx23[0]), fmaxf(mx01[1], mx23[1])),
                     fmaxf(fmaxf(mx01[2], mx23[2]), fmaxf(mx01[3], mx23[3])));
    rm = fmaxf(rm, __shfl_xor(rm, 16));
    rm = fmaxf(rm, __shfl_xor(rm, 32));
    // defer-max: rescale only if some q-row's max grew past mrun + 8
    if (__any(rm > mrun + 8.f)) {
      float mn = fmaxf(mrun, rm);
      float fac = exp2f(mrun - mn);
      mrun = mn;
      lrun *= fac;
      float facq[4];
      #pragma unroll
      for (int r = 0; r < 4; ++r) facq[r] = __shfl(fac, ((l >> 4) << 2) + r);
      #pragma unroll
      for (int nt = 0; nt < 4; ++nt)
        #pragma unroll
        for (int r = 0; r < 4; ++r) acc[nt][r] *= facq[r];
    }
    // p = 2^(s-m), row sum
    float rs = 0.f;
    #pragma unroll
    for (int t = 0; t < 4; ++t)
      #pragma unroll
      for (int r = 0; r < 4; ++r) {
        float p = exp2f(sa[t][r] - mrun);
        sa[t][r] = p;
        rs += p;
      }
    rs += __shfl_xor(rs, 16);
    rs += __shfl_xor(rs, 32);
    lrun += rs;
    // P -> LDS: row q=lr, col k=t*16+lg*4+r — packed 8B stores, A-frag layout
    #pragma unroll
    for (int t = 0; t < 4; ++t) {
      bf16x4 pk = { (bf16)sa[t][0], (bf16)sa[t][1], (bf16)sa[t][2], (bf16)sa[t][3] };
      *reinterpret_cast<bf16x4*>(pw + lr * 72 + t * 16 + lg * 4) = pk;
    }
    asm volatile("" ::: "memory");  // keep ds_write before ds_read (same-wave DS in-order)
    // PV: ctx[q][d] += P[q][k] * V[k][d]; V frag from LDS (swizzled)
    #pragma unroll
    for (int ks = 0; ks < 2; ++ks) {
      bf16x8 pa = *reinterpret_cast<const bf16x8*>(
          reinterpret_cast<const char*>(pw) + lr * 144 + ks * 64 + lg * 16);
      #pragma unroll
      for (int nt = 0; nt < 4; ++nt) {
        bf16x8 bv8 = *reinterpret_cast<const bf16x8*>(
            reinterpret_cast<const char*>(Vs) + (nt * 16 + lr) * 128 + ((ks * 4 + lg) ^ (lr & 7)) * 16);
        acc[nt] = __builtin_amdgcn_mfma_f32_16x16x32_bf16(pa, bv8, acc[nt], 0, 0, 0);
      }
    }
    __syncthreads();  // all waves done with Ks/Vs before next stage overwrites
  }

  // epilogue: fetch l for q = lg*4+r, normalize, store
  #pragma unroll
  for (int r = 0; r < 4; ++r) {
    float lq = __shfl(lrun, ((l >> 4) << 2) + r);
    float inv = 1.0f / lq;
    int sq = q16 + lg * 4 + r;
    #pragma unroll
    for (int nt = 0; nt < 4; ++nt) {
      int d = nt * 16 + lr;
      out[((bb * 2048 + sq) * 16 + hh) * 64 + d] = acc[nt][r] * inv;
    }
  }
}

extern "C" void kernel_launch(void* const* d_in, const int* in_sizes, int n_in,
                              void* d_out, int out_size, void* d_ws, size_t ws_size,
                              hipStream_t stream) {
  const float* hs   = (const float*)d_in[0];
  const float* mask = (const float*)d_in[1];
  const float* Wq   = (const float*)d_in[2];
  const float* bq   = (const float*)d_in[3];
  const float* Wk   = (const float*)d_in[4];
  const float* bk   = (const float*)d_in[5];
  const float* Wv   = (const float*)d_in[6];
  const float* bv   = (const float*)d_in[7];
  float* out = (float*)d_out;

  // workspace layout (bf16 elems): Xb 4.19M | Wb 3.15M | Qb 4.19M | Kb 4.19M | Vt 4.19M
  if (ws_size < 39845888u) return;  // need ~40 MB
  bf16* Xb = (bf16*)d_ws;
  bf16* Wb = Xb + 4194304;
  bf16* Qb = Wb + 3145728;
  bf16* Kb = Qb + 4194304;
  bf16* Vt = Kb + 4194304;

  cvt_all_kernel<<<7168, 256, 0, stream>>>(hs, Wq, Wk, Wv, Xb, Wb);
  qkv_gemm<<<dim3(24, 32), 256, 0, stream>>>(Xb, Wb, bq, bk, bv, Qb, Kb, Vt);
  attn_kernel<<<1024, 256, 0, stream>>>(Qb, Kb, Vt, mask, out);
}